// Round 10
// baseline (556.345 us; speedup 1.0000x reference)
//
#include <hip/hip_runtime.h>
#include <hip/hip_bf16.h>
#include <cstdint>
#include <cstddef>

#define Tn 4096
#define Bn 64
#define Hn 256
#define En 256
#define Vn 50257
#define D2H 512   // 2H
#define K3H 768   // 3H

typedef __attribute__((ext_vector_type(8))) short short8;
typedef __attribute__((ext_vector_type(4))) float f32x4;

__device__ __forceinline__ short bfs(float f)
{
    __hip_bfloat16 h = __float2bfloat16(f);   // RNE
    return *reinterpret_cast<short*>(&h);
}

__device__ __forceinline__ short8 pack8(const float4 x0, const float4 x1)
{
    short8 r;
    r[0] = bfs(x0.x); r[1] = bfs(x0.y); r[2] = bfs(x0.z); r[3] = bfs(x0.w);
    r[4] = bfs(x1.x); r[5] = bfs(x1.y); r[6] = bfs(x1.z); r[7] = bfs(x1.w);
    return r;
}

__device__ __forceinline__ uint2 pack4(const float4 v)
{
    uint2 r;
    r.x = (unsigned)(unsigned short)bfs(v.x) | ((unsigned)(unsigned short)bfs(v.y) << 16);
    r.y = (unsigned)(unsigned short)bfs(v.z) | ((unsigned)(unsigned short)bfs(v.w) << 16);
    return r;
}

__device__ __forceinline__ float bf2f(unsigned short u)
{
    return __uint_as_float(((unsigned)u) << 16);
}

// ---------------------------------------------------------------------------
// ws layout (float offsets):
//   baseB  : [0, 16384)            (64b x 256h)  b_attn + W1 @ h0
//   emb_g  : [16384, 32768)        (64b x 256e)
//   meta   : [32768, 40960)        float2[4096]  (m, l) per (chunk, b)
//   part   : [40960, 2138112)      [4096][512]   ctx partials
//   y      : [2138112, 2187264)    (64b x 768)   [h_new(256) | ctx(512)]
//   w2frag : [2187264, 2252800)    256 KB bf16 W2 fragments
// ---------------------------------------------------------------------------

// K1: embedding gather + baseB[b][h] = b_attn[h] + W_attn[h][0:256] . h0[b]
__global__ __launch_bounds__(256) void k1_embed_base(
    const int* __restrict__ ids, const float* __restrict__ hidden,
    const float* __restrict__ emb, const float* __restrict__ W_attn,
    const float* __restrict__ b_attn,
    float* __restrict__ baseB, float* __restrict__ emb_g)
{
    const int b = blockIdx.x, h = threadIdx.x;
    __shared__ float h0[Hn];
    h0[h] = hidden[b * Hn + h];
    __syncthreads();
    float acc = b_attn[h];
    const float* wrow = W_attn + (size_t)h * K3H;
#pragma unroll 8
    for (int k = 0; k < Hn; ++k) acc += wrow[k] * h0[k];
    baseB[b * Hn + h] = acc;
    const int id = ids[b];
    emb_g[b * En + h] = emb[(size_t)id * En + h];
}

// K1b: pack W2 = W_attn[:, 256:768] into bf16 MFMA B-fragment layout.
__global__ __launch_bounds__(64) void k1b_w2frag(
    const float* __restrict__ W_attn, unsigned short* __restrict__ w2frag)
{
    const int blk = blockIdx.x;          // nt*16 + kb
    const int nt = blk >> 4, kb = blk & 15;
    const int l = threadIdx.x, lr = l & 15, lg = l >> 4;
    const int h = nt * 16 + lr;
    const float* src = W_attn + (size_t)h * K3H + Hn + kb * 32 + lg * 8;
    float4 x0 = *reinterpret_cast<const float4*>(src);
    float4 x1 = *reinterpret_cast<const float4*>(src + 4);
    reinterpret_cast<short8*>(w2frag)[(size_t)blk * 64 + l] = pack8(x0, x1);
}

// K2F: fused scores + local-softmax + context-partial. One block = one
// (t-chunk of 64, b). enc read once, staged reg->bf16 into persistent LDS.
// NEW: B-fragments (bc) prefetched ONE CHUNK AHEAD in registers (bn), so
// COMPUTE never waits an L2 round-trip; FIFO keeps A-prefetch in flight.
__global__ __launch_bounds__(256, 2) void k2f_attn(
    const float* __restrict__ enc, const unsigned short* __restrict__ w2frag,
    const float* __restrict__ vvec, const float* __restrict__ baseB,
    float* __restrict__ part, float2* __restrict__ meta)
{
    const int tid = threadIdx.x;
    const int bx  = blockIdx.x;
    const int b   = bx & 63;
    const int cid = bx >> 6;            // t-chunk id
    const int l = tid & 63;
    const int w = tid >> 6;             // 0..3 = N-slice of 64 h
    const int lr = l & 15, lg = l >> 4;

    __shared__ unsigned short abf[64][520];   // persistent bf16 A tile
    __shared__ float red[64][5];
    __shared__ float wts[64];

    f32x4 acc[4][4];
    const f32x4 zero = {0.f, 0.f, 0.f, 0.f};
#pragma unroll
    for (int mi = 0; mi < 4; ++mi)
#pragma unroll
        for (int ni = 0; ni < 4; ++ni) acc[mi][ni] = zero;

    const short8* wf = reinterpret_cast<const short8*>(w2frag);

    const float* gbase = enc + ((size_t)(cid * 64 + w * 16 + lg) * Bn + b) * D2H
                       + lr * 4;

#define LOADREG(dst, c) do {                                                  \
    _Pragma("unroll")                                                         \
    for (int u = 0; u < 4; ++u)                                               \
        dst[u] = *reinterpret_cast<const float4*>(                            \
            gbase + (size_t)u * 131072 + (c) * 64);                           \
    } while (0)

#define WRITEC(src, c) do {                                                   \
    _Pragma("unroll")                                                         \
    for (int u = 0; u < 4; ++u)                                               \
        *reinterpret_cast<uint2*>(&abf[w * 16 + u * 4 + lg][(c) * 64 + lr * 4])\
            = pack4(src[u]);                                                  \
    } while (0)

#define COMPUTE_KB(kb, bfr) do {                                              \
    _Pragma("unroll")                                                         \
    for (int mi = 0; mi < 4; ++mi) {                                          \
        short8 a = *reinterpret_cast<const short8*>(                          \
            &abf[mi * 16 + lr][(kb) * 32 + lg * 8]);                          \
        _Pragma("unroll")                                                     \
        for (int ni = 0; ni < 4; ++ni)                                        \
            acc[mi][ni] = __builtin_amdgcn_mfma_f32_16x16x32_bf16(            \
                a, bfr[ni], acc[mi][ni], 0, 0, 0);                            \
    } } while (0)

    float4 st0[4], st1[4];
    // prologue: A chunks 0,1 in flight; B chunk 0 (bc) in flight
    LOADREG(st0, 0);
    LOADREG(st1, 1);
    short8 bc0[4], bc1[4];
#pragma unroll
    for (int ni = 0; ni < 4; ++ni)
        bc0[ni] = wf[(size_t)(((w * 4 + ni) * 16) + 0) * 64 + l];
#pragma unroll
    for (int ni = 0; ni < 4; ++ni)
        bc1[ni] = wf[(size_t)(((w * 4 + ni) * 16) + 1) * 64 + l];
    WRITEC(st0, 0);                      // waits st0 only (oldest, FIFO)
    asm volatile("s_waitcnt lgkmcnt(0)" ::: "memory");
    __builtin_amdgcn_s_barrier();
    __builtin_amdgcn_sched_barrier(0);

#pragma unroll
    for (int kc = 0; kc < 8; ++kc) {
        // next chunk's B-fragments issued NOW, consumed next iteration
        short8 bn0[4], bn1[4];
        if (kc < 7) {
#pragma unroll
            for (int ni = 0; ni < 4; ++ni)
                bn0[ni] = wf[(size_t)(((w * 4 + ni) * 16) + 2 * kc + 2) * 64 + l];
#pragma unroll
            for (int ni = 0; ni < 4; ++ni)
                bn1[ni] = wf[(size_t)(((w * 4 + ni) * 16) + 2 * kc + 3) * 64 + l];
        }
        if (kc < 6) {
            if ((kc & 1) == 0) LOADREG(st0, kc + 2);
            else               LOADREG(st1, kc + 2);
        }
        COMPUTE_KB(2 * kc,     bc0);     // bc issued last iter: no L2 stall
        COMPUTE_KB(2 * kc + 1, bc1);
        if (kc < 7) {
            if ((kc & 1) == 0) WRITEC(st1, kc + 1);
            else               WRITEC(st0, kc + 1);
        }
        asm volatile("s_waitcnt lgkmcnt(0)" ::: "memory");
        __builtin_amdgcn_s_barrier();
        __builtin_amdgcn_sched_barrier(0);
        if (kc < 7) {
#pragma unroll
            for (int ni = 0; ni < 4; ++ni) { bc0[ni] = bn0[ni]; bc1[ni] = bn1[ni]; }
        }
    }
#undef LOADREG
#undef WRITEC
#undef COMPUTE_KB

    // scores epilogue
    float psum[4][4];
#pragma unroll
    for (int mi = 0; mi < 4; ++mi)
#pragma unroll
        for (int r = 0; r < 4; ++r) psum[mi][r] = 0.f;
#pragma unroll
    for (int ni = 0; ni < 4; ++ni) {
        const int h = w * 64 + ni * 16 + lr;
        const float vh = vvec[h];
        const float bt = baseB[b * Hn + h];
#pragma unroll
        for (int mi = 0; mi < 4; ++mi)
#pragma unroll
            for (int r = 0; r < 4; ++r)
                psum[mi][r] += vh * tanhf(acc[mi][ni][r] + bt);
    }
#pragma unroll
    for (int d = 1; d < 16; d <<= 1)
#pragma unroll
        for (int mi = 0; mi < 4; ++mi)
#pragma unroll
            for (int r = 0; r < 4; ++r)
                psum[mi][r] += __shfl_xor(psum[mi][r], d, 64);
    if (lr == 0) {
#pragma unroll
        for (int mi = 0; mi < 4; ++mi)
#pragma unroll
            for (int r = 0; r < 4; ++r)
                red[mi * 16 + lg * 4 + r][w] = psum[mi][r];
    }
    __syncthreads();

    if (tid < 64) {
        float s = red[tid][0] + red[tid][1] + red[tid][2] + red[tid][3];
        float m = s;
#pragma unroll
        for (int d = 1; d < 64; d <<= 1) m = fmaxf(m, __shfl_xor(m, d, 64));
        const float e = expf(s - m);
        float lsum = e;
#pragma unroll
        for (int d = 1; d < 64; d <<= 1) lsum += __shfl_xor(lsum, d, 64);
        wts[tid] = e;
        if (tid == 0) meta[bx] = make_float2(m, lsum);
    }
    __syncthreads();

    // context partial from the persistent bf16 tile
    const int d0 = tid * 2;
    float c0 = 0.f, c1 = 0.f;
#pragma unroll 4
    for (int t = 0; t < 64; ++t) {
        const float wt = wts[t];
        const unsigned u = *reinterpret_cast<const unsigned*>(&abf[t][d0]);
        c0 += wt * bf2f((unsigned short)(u & 0xffffu));
        c1 += wt * bf2f((unsigned short)(u >> 16));
    }
    float* pp = part + (size_t)bx * 512 + d0;
    pp[0] = c0; pp[1] = c1;
}

// K5N: cross-chunk softmax combine with rescaling -> ctx into y[b][256:768]
__global__ __launch_bounds__(256) void k5n_combine(
    const float* __restrict__ part, const float2* __restrict__ meta,
    float* __restrict__ y)
{
    const int b = blockIdx.x, tid = threadIdx.x;
    __shared__ float sc[64];
    if (tid < 64) {
        const float2 ml = meta[(size_t)tid * 64 + b];
        float M = ml.x;
#pragma unroll
        for (int d = 1; d < 64; d <<= 1) M = fmaxf(M, __shfl_xor(M, d, 64));
        const float e = expf(ml.x - M);
        float L = e * ml.y;
#pragma unroll
        for (int d = 1; d < 64; d <<= 1) L += __shfl_xor(L, d, 64);
        sc[tid] = e / L;
    }
    __syncthreads();
    const int d0 = tid * 2;
    float c0 = 0.f, c1 = 0.f;
#pragma unroll 4
    for (int c = 0; c < 64; ++c) {
        const float s = sc[c];
        const float2 p = *reinterpret_cast<const float2*>(
            part + ((size_t)c * 64 + b) * 512 + d0);
        c0 += s * p.x; c1 += s * p.y;
    }
    y[(size_t)b * K3H + Hn + d0]     = c0;
    y[(size_t)b * K3H + Hn + d0 + 1] = c1;
}

// K6: combine + GRU
__global__ __launch_bounds__(256) void k6_gru(
    const float* __restrict__ hidden, const float* __restrict__ emb_g,
    const float* __restrict__ W_comb, const float* __restrict__ b_comb,
    const float* __restrict__ W_ih, const float* __restrict__ W_hh,
    const float* __restrict__ b_ih, const float* __restrict__ b_hh,
    float* __restrict__ y, float* __restrict__ out_hidden)
{
    const int b = blockIdx.x, h = threadIdx.x;
    __shared__ float in_[K3H];
    __shared__ float h0[Hn];
    __shared__ float comb[Hn];
    __shared__ float gx[K3H], gh[K3H];
    in_[h]       = y[(size_t)b * K3H + Hn + h];
    in_[256 + h] = y[(size_t)b * K3H + Hn + 256 + h];
    in_[512 + h] = emb_g[b * En + h];
    h0[h] = hidden[b * Hn + h];
    __syncthreads();
    {
        float c = b_comb[h];
        const float* wr = W_comb + (size_t)h * K3H;
#pragma unroll 8
        for (int k = 0; k < K3H; ++k) c += wr[k] * in_[k];
        comb[h] = c;
    }
    __syncthreads();
#pragma unroll
    for (int p = 0; p < 3; ++p) {
        const int g = p * 256 + h;
        float a = b_ih[g], bh = b_hh[g];
        const float* wi = W_ih + (size_t)g * Hn;
        const float* wh = W_hh + (size_t)g * Hn;
#pragma unroll 8
        for (int k = 0; k < Hn; ++k) { a += wi[k] * comb[k]; bh += wh[k] * h0[k]; }
        gx[g] = a; gh[g] = bh;
    }
    __syncthreads();
    const float r = 1.f / (1.f + expf(-(gx[h] + gh[h])));
    const float z = 1.f / (1.f + expf(-(gx[256 + h] + gh[256 + h])));
    const float n = tanhf(gx[512 + h] + r * gh[512 + h]);
    const float hn = (1.f - z) * n + z * h0[h];
    y[(size_t)b * K3H + h] = hn;
    out_hidden[b * Hn + h] = hn;
}

// K7: logits GEMM, float4 LDS micro-kernel. v = vbase + tv + 16i (stride-1
// rows -> 2-way bank aliasing = free); tiles [64][36] (16B-aligned rows).
__global__ __launch_bounds__(256) void k7_logits(
    const float* __restrict__ W_out, const float* __restrict__ b_out,
    const float* __restrict__ y, float* __restrict__ out)
{
    const int vbase = blockIdx.x * 64;
    const int tv = threadIdx.x & 15;
    const int tb = threadIdx.x >> 4;
    __shared__ float lw[64][36];
    __shared__ float ly[64][36];
    float acc[4][4] = {};
    for (int kc = 0; kc < 24; ++kc) {
        __syncthreads();
#pragma unroll
        for (int u = 0; u < 8; ++u) {
            int idx = threadIdx.x + u * 256;
            int r = idx >> 5, c = idx & 31;
            int vv = vbase + r;
            lw[r][c] = (vv < Vn) ? W_out[(size_t)vv * K3H + kc * 32 + c] : 0.f;
        }
#pragma unroll
        for (int u = 0; u < 8; ++u) {
            int idx = threadIdx.x + u * 256;
            int bb = idx >> 5, k = idx & 31;
            ly[bb][k] = y[(size_t)bb * K3H + kc * 32 + k];
        }
        __syncthreads();
#pragma unroll
        for (int k4 = 0; k4 < 8; ++k4) {
            float4 wv[4], yv[4];
#pragma unroll
            for (int i = 0; i < 4; ++i)
                wv[i] = *reinterpret_cast<const float4*>(&lw[tv + i * 16][k4 * 4]);
#pragma unroll
            for (int j = 0; j < 4; ++j)
                yv[j] = *reinterpret_cast<const float4*>(&ly[tb + j * 16][k4 * 4]);
#pragma unroll
            for (int i = 0; i < 4; ++i)
#pragma unroll
                for (int j = 0; j < 4; ++j)
                    acc[i][j] += wv[i].x * yv[j].x + wv[i].y * yv[j].y
                               + wv[i].z * yv[j].z + wv[i].w * yv[j].w;
        }
    }
#pragma unroll
    for (int i = 0; i < 4; ++i) {
        const int vv = vbase + tv + i * 16;
        if (vv < Vn) {
            const float bo = b_out[vv];
#pragma unroll
            for (int j = 0; j < 4; ++j) {
                const int b = tb + j * 16;
                out[(size_t)b * Vn + vv] = acc[i][j] + bo;
            }
        }
    }
}

// K8: log_softmax over V per row
__global__ __launch_bounds__(1024) void k8_logsoftmax(float* __restrict__ out)
{
    const int b = blockIdx.x;
    float* row = out + (size_t)b * Vn;
    __shared__ float red[1024];
    float m = -1e30f;
    for (int i = threadIdx.x; i < Vn; i += 1024) m = fmaxf(m, row[i]);
    red[threadIdx.x] = m; __syncthreads();
    for (int s = 512; s > 0; s >>= 1) {
        if (threadIdx.x < s) red[threadIdx.x] = fmaxf(red[threadIdx.x], red[threadIdx.x + s]);
        __syncthreads();
    }
    m = red[0]; __syncthreads();
    float l = 0.f;
    for (int i = threadIdx.x; i < Vn; i += 1024) l += expf(row[i] - m);
    red[threadIdx.x] = l; __syncthreads();
    for (int s = 512; s > 0; s >>= 1) {
        if (threadIdx.x < s) red[threadIdx.x] += red[threadIdx.x + s];
        __syncthreads();
    }
    l = red[0];
    const float off = m + logf(l);
    for (int i = threadIdx.x; i < Vn; i += 1024) row[i] = row[i] - off;
}

extern "C" void kernel_launch(void* const* d_in, const int* in_sizes, int n_in,
                              void* d_out, int out_size, void* d_ws, size_t ws_size,
                              hipStream_t stream)
{
    const int*   ids    = (const int*)d_in[0];
    const float* hidden = (const float*)d_in[1];
    const float* enc    = (const float*)d_in[2];
    const float* emb    = (const float*)d_in[3];
    const float* W_attn = (const float*)d_in[4];
    const float* b_attn = (const float*)d_in[5];
    const float* vvec   = (const float*)d_in[6];
    const float* W_comb = (const float*)d_in[7];
    const float* b_comb = (const float*)d_in[8];
    const float* W_ih   = (const float*)d_in[9];
    const float* W_hh   = (const float*)d_in[10];
    const float* b_ih   = (const float*)d_in[11];
    const float* b_hh   = (const float*)d_in[12];
    const float* W_out  = (const float*)d_in[13];
    const float* b_out  = (const float*)d_in[14];

    float* out = (float*)d_out;
    float* ws = (float*)d_ws;
    float*  baseB = ws;                               // 16384
    float*  emb_g = ws + 16384;                       // 16384
    float2* meta  = (float2*)(ws + 32768);            // 4096 float2
    float*  part  = ws + 40960;                       // 2097152
    float*  y     = ws + 2138112;                     // 49152
    unsigned short* w2frag = (unsigned short*)(ws + 2187264); // 131072 bf16

    hipLaunchKernelGGL(k1_embed_base, dim3(Bn), dim3(256), 0, stream,
                       ids, hidden, emb, W_attn, b_attn, baseB, emb_g);
    hipLaunchKernelGGL(k1b_w2frag, dim3(256), dim3(64), 0, stream,
                       W_attn, w2frag);
    hipLaunchKernelGGL(k2f_attn, dim3(4096), dim3(256), 0, stream,
                       enc, w2frag, vvec, baseB, part, meta);
    hipLaunchKernelGGL(k5n_combine, dim3(Bn), dim3(256), 0, stream,
                       part, meta, y);
    hipLaunchKernelGGL(k6_gru, dim3(Bn), dim3(256), 0, stream,
                       hidden, emb_g, W_comb, b_comb, W_ih, W_hh, b_ih, b_hh,
                       y, out + (size_t)Bn * Vn);
    hipLaunchKernelGGL(k7_logits, dim3((Vn + 63) / 64), dim3(256), 0, stream,
                       W_out, b_out, y, out);
    hipLaunchKernelGGL(k8_logsoftmax, dim3(Bn), dim3(1024), 0, stream, out);
}

// Round 11
// 354.530 us; speedup vs baseline: 1.5692x; 1.5692x over previous
//
#include <hip/hip_runtime.h>
#include <hip/hip_bf16.h>
#include <cstdint>
#include <cstddef>

#define Tn 4096
#define Bn 64
#define Hn 256
#define En 256
#define Vn 50257
#define D2H 512   // 2H
#define K3H 768   // 3H

typedef __attribute__((ext_vector_type(8))) short short8;
typedef __attribute__((ext_vector_type(4))) float f32x4;

__device__ __forceinline__ short bfs(float f)
{
    __hip_bfloat16 h = __float2bfloat16(f);   // RNE
    return *reinterpret_cast<short*>(&h);
}

__device__ __forceinline__ short8 pack8(const float4 x0, const float4 x1)
{
    short8 r;
    r[0] = bfs(x0.x); r[1] = bfs(x0.y); r[2] = bfs(x0.z); r[3] = bfs(x0.w);
    r[4] = bfs(x1.x); r[5] = bfs(x1.y); r[6] = bfs(x1.z); r[7] = bfs(x1.w);
    return r;
}

__device__ __forceinline__ uint2 pack4(const float4 v)
{
    uint2 r;
    r.x = (unsigned)(unsigned short)bfs(v.x) | ((unsigned)(unsigned short)bfs(v.y) << 16);
    r.y = (unsigned)(unsigned short)bfs(v.z) | ((unsigned)(unsigned short)bfs(v.w) << 16);
    return r;
}

__device__ __forceinline__ float bf2f(unsigned short u)
{
    return __uint_as_float(((unsigned)u) << 16);
}

// ---------------------------------------------------------------------------
// ws layout (float offsets):
//   baseB  : [0, 16384)            (64b x 256h)  b_attn + W1 @ h0
//   emb_g  : [16384, 32768)        (64b x 256e)
//   meta   : [32768, 40960)        float2[4096]  (m, l) per (chunk, b)
//   part   : [40960, 2138112)      [4096][512]   ctx partials
//   y      : [2138112, 2187264)    (64b x 768)   [h_new(256) | ctx(512)]
//   w2frag : [2187264, 2252800)    256 KB bf16 W2 fragments
//   yfrag  : [2252800, 2277376)    98 KB bf16 y fragments (96 tiles)
// ---------------------------------------------------------------------------

// K1: embedding gather + baseB[b][h] = b_attn[h] + W_attn[h][0:256] . h0[b]
__global__ __launch_bounds__(256) void k1_embed_base(
    const int* __restrict__ ids, const float* __restrict__ hidden,
    const float* __restrict__ emb, const float* __restrict__ W_attn,
    const float* __restrict__ b_attn,
    float* __restrict__ baseB, float* __restrict__ emb_g)
{
    const int b = blockIdx.x, h = threadIdx.x;
    __shared__ float h0[Hn];
    h0[h] = hidden[b * Hn + h];
    __syncthreads();
    float acc = b_attn[h];
    const float* wrow = W_attn + (size_t)h * K3H;
#pragma unroll 8
    for (int k = 0; k < Hn; ++k) acc += wrow[k] * h0[k];
    baseB[b * Hn + h] = acc;
    const int id = ids[b];
    emb_g[b * En + h] = emb[(size_t)id * En + h];
}

// K1b: pack W2 = W_attn[:, 256:768] into bf16 MFMA B-fragment layout.
__global__ __launch_bounds__(64) void k1b_w2frag(
    const float* __restrict__ W_attn, unsigned short* __restrict__ w2frag)
{
    const int blk = blockIdx.x;          // nt*16 + kb
    const int nt = blk >> 4, kb = blk & 15;
    const int l = threadIdx.x, lr = l & 15, lg = l >> 4;
    const int h = nt * 16 + lr;
    const float* src = W_attn + (size_t)h * K3H + Hn + kb * 32 + lg * 8;
    float4 x0 = *reinterpret_cast<const float4*>(src);
    float4 x1 = *reinterpret_cast<const float4*>(src + 4);
    reinterpret_cast<short8*>(w2frag)[(size_t)blk * 64 + l] = pack8(x0, x1);
}

// K2F: fused scores + local-softmax + context-partial (round-8 exact state).
__global__ __launch_bounds__(256, 2) void k2f_attn(
    const float* __restrict__ enc, const unsigned short* __restrict__ w2frag,
    const float* __restrict__ vvec, const float* __restrict__ baseB,
    float* __restrict__ part, float2* __restrict__ meta)
{
    const int tid = threadIdx.x;
    const int bx  = blockIdx.x;
    const int b   = bx & 63;
    const int cid = bx >> 6;            // t-chunk id
    const int l = tid & 63;
    const int w = tid >> 6;             // 0..3 = N-slice of 64 h
    const int lr = l & 15, lg = l >> 4;

    __shared__ unsigned short abf[64][520];   // persistent bf16 A tile
    __shared__ float red[64][5];
    __shared__ float wts[64];

    f32x4 acc[4][4];
    const f32x4 zero = {0.f, 0.f, 0.f, 0.f};
#pragma unroll
    for (int mi = 0; mi < 4; ++mi)
#pragma unroll
        for (int ni = 0; ni < 4; ++ni) acc[mi][ni] = zero;

    const short8* wf = reinterpret_cast<const short8*>(w2frag);

    const float* gbase = enc + ((size_t)(cid * 64 + w * 16 + lg) * Bn + b) * D2H
                       + lr * 4;

#define LOADREG(dst, c) do {                                                  \
    _Pragma("unroll")                                                         \
    for (int u = 0; u < 4; ++u)                                               \
        dst[u] = *reinterpret_cast<const float4*>(                            \
            gbase + (size_t)u * 131072 + (c) * 64);                           \
    } while (0)

#define WRITEC(src, c) do {                                                   \
    _Pragma("unroll")                                                         \
    for (int u = 0; u < 4; ++u)                                               \
        *reinterpret_cast<uint2*>(&abf[w * 16 + u * 4 + lg][(c) * 64 + lr * 4])\
            = pack4(src[u]);                                                  \
    } while (0)

#define COMPUTE_KB(kb, bfr) do {                                              \
    _Pragma("unroll")                                                         \
    for (int mi = 0; mi < 4; ++mi) {                                          \
        short8 a = *reinterpret_cast<const short8*>(                          \
            &abf[mi * 16 + lr][(kb) * 32 + lg * 8]);                          \
        _Pragma("unroll")                                                     \
        for (int ni = 0; ni < 4; ++ni)                                        \
            acc[mi][ni] = __builtin_amdgcn_mfma_f32_16x16x32_bf16(            \
                a, bfr[ni], acc[mi][ni], 0, 0, 0);                            \
    } } while (0)

    float4 st0[4], st1[4];
    LOADREG(st0, 0);
    LOADREG(st1, 1);
    WRITEC(st0, 0);
    asm volatile("s_waitcnt lgkmcnt(0)" ::: "memory");
    __builtin_amdgcn_s_barrier();
    __builtin_amdgcn_sched_barrier(0);

#pragma unroll
    for (int kc = 0; kc < 8; ++kc) {
        short8 bfr0[4], bfr1[4];
#pragma unroll
        for (int ni = 0; ni < 4; ++ni)
            bfr0[ni] = wf[(size_t)(((w * 4 + ni) * 16) + 2 * kc) * 64 + l];
#pragma unroll
        for (int ni = 0; ni < 4; ++ni)
            bfr1[ni] = wf[(size_t)(((w * 4 + ni) * 16) + 2 * kc + 1) * 64 + l];
        __builtin_amdgcn_sched_barrier(0);
        if (kc < 6) {
            if ((kc & 1) == 0) LOADREG(st0, kc + 2);
            else               LOADREG(st1, kc + 2);
        }
        COMPUTE_KB(2 * kc,     bfr0);
        COMPUTE_KB(2 * kc + 1, bfr1);
        if (kc < 7) {
            if ((kc & 1) == 0) WRITEC(st1, kc + 1);
            else               WRITEC(st0, kc + 1);
        }
        asm volatile("s_waitcnt lgkmcnt(0)" ::: "memory");
        __builtin_amdgcn_s_barrier();
        __builtin_amdgcn_sched_barrier(0);
    }
#undef LOADREG
#undef WRITEC
#undef COMPUTE_KB

    float psum[4][4];
#pragma unroll
    for (int mi = 0; mi < 4; ++mi)
#pragma unroll
        for (int r = 0; r < 4; ++r) psum[mi][r] = 0.f;
#pragma unroll
    for (int ni = 0; ni < 4; ++ni) {
        const int h = w * 64 + ni * 16 + lr;
        const float vh = vvec[h];
        const float bt = baseB[b * Hn + h];
#pragma unroll
        for (int mi = 0; mi < 4; ++mi)
#pragma unroll
            for (int r = 0; r < 4; ++r)
                psum[mi][r] += vh * tanhf(acc[mi][ni][r] + bt);
    }
#pragma unroll
    for (int d = 1; d < 16; d <<= 1)
#pragma unroll
        for (int mi = 0; mi < 4; ++mi)
#pragma unroll
            for (int r = 0; r < 4; ++r)
                psum[mi][r] += __shfl_xor(psum[mi][r], d, 64);
    if (lr == 0) {
#pragma unroll
        for (int mi = 0; mi < 4; ++mi)
#pragma unroll
            for (int r = 0; r < 4; ++r)
                red[mi * 16 + lg * 4 + r][w] = psum[mi][r];
    }
    __syncthreads();

    if (tid < 64) {
        float s = red[tid][0] + red[tid][1] + red[tid][2] + red[tid][3];
        float m = s;
#pragma unroll
        for (int d = 1; d < 64; d <<= 1) m = fmaxf(m, __shfl_xor(m, d, 64));
        const float e = expf(s - m);
        float lsum = e;
#pragma unroll
        for (int d = 1; d < 64; d <<= 1) lsum += __shfl_xor(lsum, d, 64);
        wts[tid] = e;
        if (tid == 0) meta[bx] = make_float2(m, lsum);
    }
    __syncthreads();

    const int d0 = tid * 2;
    float c0 = 0.f, c1 = 0.f;
#pragma unroll 4
    for (int t = 0; t < 64; ++t) {
        const float wt = wts[t];
        const unsigned u = *reinterpret_cast<const unsigned*>(&abf[t][d0]);
        c0 += wt * bf2f((unsigned short)(u & 0xffffu));
        c1 += wt * bf2f((unsigned short)(u >> 16));
    }
    float* pp = part + (size_t)bx * 512 + d0;
    pp[0] = c0; pp[1] = c1;
}

// K5N: cross-chunk softmax combine with rescaling -> ctx into y[b][256:768]
__global__ __launch_bounds__(256) void k5n_combine(
    const float* __restrict__ part, const float2* __restrict__ meta,
    float* __restrict__ y)
{
    const int b = blockIdx.x, tid = threadIdx.x;
    __shared__ float sc[64];
    if (tid < 64) {
        const float2 ml = meta[(size_t)tid * 64 + b];
        float M = ml.x;
#pragma unroll
        for (int d = 1; d < 64; d <<= 1) M = fmaxf(M, __shfl_xor(M, d, 64));
        const float e = expf(ml.x - M);
        float L = e * ml.y;
#pragma unroll
        for (int d = 1; d < 64; d <<= 1) L += __shfl_xor(L, d, 64);
        sc[tid] = e / L;
    }
    __syncthreads();
    const int d0 = tid * 2;
    float c0 = 0.f, c1 = 0.f;
#pragma unroll 4
    for (int c = 0; c < 64; ++c) {
        const float s = sc[c];
        const float2 p = *reinterpret_cast<const float2*>(
            part + ((size_t)c * 64 + b) * 512 + d0);
        c0 += s * p.x; c1 += s * p.y;
    }
    y[(size_t)b * K3H + Hn + d0]     = c0;
    y[(size_t)b * K3H + Hn + d0 + 1] = c1;
}

// K6: combine + GRU
__global__ __launch_bounds__(256) void k6_gru(
    const float* __restrict__ hidden, const float* __restrict__ emb_g,
    const float* __restrict__ W_comb, const float* __restrict__ b_comb,
    const float* __restrict__ W_ih, const float* __restrict__ W_hh,
    const float* __restrict__ b_ih, const float* __restrict__ b_hh,
    float* __restrict__ y, float* __restrict__ out_hidden)
{
    const int b = blockIdx.x, h = threadIdx.x;
    __shared__ float in_[K3H];
    __shared__ float h0[Hn];
    __shared__ float comb[Hn];
    __shared__ float gx[K3H], gh[K3H];
    in_[h]       = y[(size_t)b * K3H + Hn + h];
    in_[256 + h] = y[(size_t)b * K3H + Hn + 256 + h];
    in_[512 + h] = emb_g[b * En + h];
    h0[h] = hidden[b * Hn + h];
    __syncthreads();
    {
        float c = b_comb[h];
        const float* wr = W_comb + (size_t)h * K3H;
#pragma unroll 8
        for (int k = 0; k < K3H; ++k) c += wr[k] * in_[k];
        comb[h] = c;
    }
    __syncthreads();
#pragma unroll
    for (int p = 0; p < 3; ++p) {
        const int g = p * 256 + h;
        float a = b_ih[g], bh = b_hh[g];
        const float* wi = W_ih + (size_t)g * Hn;
        const float* wh = W_hh + (size_t)g * Hn;
#pragma unroll 8
        for (int k = 0; k < Hn; ++k) { a += wi[k] * comb[k]; bh += wh[k] * h0[k]; }
        gx[g] = a; gh[g] = bh;
    }
    __syncthreads();
    const float r = 1.f / (1.f + expf(-(gx[h] + gh[h])));
    const float z = 1.f / (1.f + expf(-(gx[256 + h] + gh[256 + h])));
    const float n = tanhf(gx[512 + h] + r * gh[512 + h]);
    const float hn = (1.f - z) * n + z * h0[h];
    y[(size_t)b * K3H + h] = hn;
    out_hidden[b * Hn + h] = hn;
}

// K7Y: pack y (64b x 768k) into bf16 MFMA B-fragment layout.
// yfrag[(ni*24 + kb)*64 + lane]: b = ni*16 + (lane&15), k = kb*32 + (lane>>4)*8 + j
__global__ __launch_bounds__(64) void k7y_pack(
    const float* __restrict__ y, unsigned short* __restrict__ yfrag)
{
    const int blk = blockIdx.x;          // 0..95 = ni*24 + kb
    const int ni = blk / 24, kb = blk % 24;
    const int l = threadIdx.x, lr = l & 15, lg = l >> 4;
    const int b = ni * 16 + lr;
    const float* src = y + (size_t)b * K3H + kb * 32 + lg * 8;
    float4 x0 = *reinterpret_cast<const float4*>(src);
    float4 x1 = *reinterpret_cast<const float4*>(src + 4);
    reinterpret_cast<short8*>(yfrag)[(size_t)blk * 64 + l] = pack8(x0, x1);
}

// K7: logits GEMM via MFMA. A = W_out rows streamed global->reg->bf16
// (no LDS staging, no K-loop barriers; TLP hides latency). B = yfrag
// (98 KB, L2-resident). Same error-cancelling A/B k-map as k2f.
// Epilogue: LDS transpose for coalesced stores, b_out fused.
__global__ __launch_bounds__(256) void k7_logits(
    const float* __restrict__ W_out, const float* __restrict__ b_out,
    const unsigned short* __restrict__ yfrag, float* __restrict__ out)
{
    const int tid = threadIdx.x;
    const int vbase = blockIdx.x * 64;
    const int l = tid & 63, w = tid >> 6;    // wave w owns v rows w*16..+15
    const int lr = l & 15, lg = l >> 4;

    const short8* yf = reinterpret_cast<const short8*>(yfrag);

    f32x4 acc[4];
    const f32x4 zero = {0.f, 0.f, 0.f, 0.f};
#pragma unroll
    for (int ni = 0; ni < 4; ++ni) acc[ni] = zero;

    int v = vbase + w * 16 + lr;
    if (v >= Vn) v = Vn - 1;                 // clamp (values discarded)
    const float* wrow = W_out + (size_t)v * K3H + lg * 8;

#pragma unroll 4
    for (int kb = 0; kb < 24; ++kb) {
        float4 x0 = *reinterpret_cast<const float4*>(wrow + kb * 32);
        float4 x1 = *reinterpret_cast<const float4*>(wrow + kb * 32 + 4);
        short8 a = pack8(x0, x1);
#pragma unroll
        for (int ni = 0; ni < 4; ++ni) {
            short8 bf = yf[(size_t)(ni * 24 + kb) * 64 + l];
            acc[ni] = __builtin_amdgcn_mfma_f32_16x16x32_bf16(
                a, bf, acc[ni], 0, 0, 0);
        }
    }

    // transpose via LDS: lt[v_local][b]
    __shared__ float lt[64][65];
#pragma unroll
    for (int ni = 0; ni < 4; ++ni)
#pragma unroll
        for (int r = 0; r < 4; ++r)
            lt[w * 16 + lg * 4 + r][ni * 16 + lr] = acc[ni][r];
    __syncthreads();

    // coalesced store: consecutive lanes -> consecutive v
#pragma unroll
    for (int u = 0; u < 16; ++u) {
        const int idx = tid + u * 256;       // 0..4095
        const int bb = idx >> 6, vv = idx & 63;
        const int vo = vbase + vv;
        if (vo < Vn)
            out[(size_t)bb * Vn + vo] = lt[vv][bb] + b_out[vo];
    }
}

// K8: log_softmax over V per row
__global__ __launch_bounds__(1024) void k8_logsoftmax(float* __restrict__ out)
{
    const int b = blockIdx.x;
    float* row = out + (size_t)b * Vn;
    __shared__ float red[1024];
    float m = -1e30f;
    for (int i = threadIdx.x; i < Vn; i += 1024) m = fmaxf(m, row[i]);
    red[threadIdx.x] = m; __syncthreads();
    for (int s = 512; s > 0; s >>= 1) {
        if (threadIdx.x < s) red[threadIdx.x] = fmaxf(red[threadIdx.x], red[threadIdx.x + s]);
        __syncthreads();
    }
    m = red[0]; __syncthreads();
    float l = 0.f;
    for (int i = threadIdx.x; i < Vn; i += 1024) l += expf(row[i] - m);
    red[threadIdx.x] = l; __syncthreads();
    for (int s = 512; s > 0; s >>= 1) {
        if (threadIdx.x < s) red[threadIdx.x] += red[threadIdx.x + s];
        __syncthreads();
    }
    l = red[0];
    const float off = m + logf(l);
    for (int i = threadIdx.x; i < Vn; i += 1024) row[i] = row[i] - off;
}

extern "C" void kernel_launch(void* const* d_in, const int* in_sizes, int n_in,
                              void* d_out, int out_size, void* d_ws, size_t ws_size,
                              hipStream_t stream)
{
    const int*   ids    = (const int*)d_in[0];
    const float* hidden = (const float*)d_in[1];
    const float* enc    = (const float*)d_in[2];
    const float* emb    = (const float*)d_in[3];
    const float* W_attn = (const float*)d_in[4];
    const float* b_attn = (const float*)d_in[5];
    const float* vvec   = (const float*)d_in[6];
    const float* W_comb = (const float*)d_in[7];
    const float* b_comb = (const float*)d_in[8];
    const float* W_ih   = (const float*)d_in[9];
    const float* W_hh   = (const float*)d_in[10];
    const float* b_ih   = (const float*)d_in[11];
    const float* b_hh   = (const float*)d_in[12];
    const float* W_out  = (const float*)d_in[13];
    const float* b_out  = (const float*)d_in[14];

    float* out = (float*)d_out;
    float* ws = (float*)d_ws;
    float*  baseB = ws;                               // 16384
    float*  emb_g = ws + 16384;                       // 16384
    float2* meta  = (float2*)(ws + 32768);            // 4096 float2
    float*  part  = ws + 40960;                       // 2097152
    float*  y     = ws + 2138112;                     // 49152
    unsigned short* w2frag = (unsigned short*)(ws + 2187264); // 131072 bf16
    unsigned short* yfrag  = (unsigned short*)(ws + 2252800); // 49152 bf16

    hipLaunchKernelGGL(k1_embed_base, dim3(Bn), dim3(256), 0, stream,
                       ids, hidden, emb, W_attn, b_attn, baseB, emb_g);
    hipLaunchKernelGGL(k1b_w2frag, dim3(256), dim3(64), 0, stream,
                       W_attn, w2frag);
    hipLaunchKernelGGL(k2f_attn, dim3(4096), dim3(256), 0, stream,
                       enc, w2frag, vvec, baseB, part, meta);
    hipLaunchKernelGGL(k5n_combine, dim3(Bn), dim3(256), 0, stream,
                       part, meta, y);
    hipLaunchKernelGGL(k6_gru, dim3(Bn), dim3(256), 0, stream,
                       hidden, emb_g, W_comb, b_comb, W_ih, W_hh, b_ih, b_hh,
                       y, out + (size_t)Bn * Vn);
    hipLaunchKernelGGL(k7y_pack, dim3(96), dim3(64), 0, stream, y, yfrag);
    hipLaunchKernelGGL(k7_logits, dim3((Vn + 63) / 64), dim3(256), 0, stream,
                       W_out, b_out, yfrag, out);
    hipLaunchKernelGGL(k8_logsoftmax, dim3(Bn), dim3(1024), 0, stream, out);
}

// Round 12
// 341.843 us; speedup vs baseline: 1.6275x; 1.0371x over previous
//
#include <hip/hip_runtime.h>
#include <hip/hip_bf16.h>
#include <cstdint>
#include <cstddef>

#define Tn 4096
#define Bn 64
#define Hn 256
#define En 256
#define Vn 50257
#define D2H 512   // 2H
#define K3H 768   // 3H

typedef __attribute__((ext_vector_type(8))) short short8;
typedef __attribute__((ext_vector_type(4))) float f32x4;

__device__ __forceinline__ short bfs(float f)
{
    __hip_bfloat16 h = __float2bfloat16(f);   // RNE
    return *reinterpret_cast<short*>(&h);
}

__device__ __forceinline__ short8 pack8(const float4 x0, const float4 x1)
{
    short8 r;
    r[0] = bfs(x0.x); r[1] = bfs(x0.y); r[2] = bfs(x0.z); r[3] = bfs(x0.w);
    r[4] = bfs(x1.x); r[5] = bfs(x1.y); r[6] = bfs(x1.z); r[7] = bfs(x1.w);
    return r;
}

__device__ __forceinline__ uint2 pack4(const float4 v)
{
    uint2 r;
    r.x = (unsigned)(unsigned short)bfs(v.x) | ((unsigned)(unsigned short)bfs(v.y) << 16);
    r.y = (unsigned)(unsigned short)bfs(v.z) | ((unsigned)(unsigned short)bfs(v.w) << 16);
    return r;
}

__device__ __forceinline__ float bf2f(unsigned short u)
{
    return __uint_as_float(((unsigned)u) << 16);
}

// ---------------------------------------------------------------------------
// ws layout (float offsets):
//   baseB  : [0, 16384)            (64b x 256h)
//   emb_g  : [16384, 32768)        (64b x 256e)
//   meta   : [32768, 40960)        float2[4096]  (m, l) per (chunk, b)
//   part   : [40960, 2138112)      [4096][512]   ctx partials
//   y      : [2138112, 2187264)    (64b x 768)
//   w2frag : [2187264, 2252800)    256 KB bf16 W2 fragments
//   yfrag  : [2252800, 2277376)    98 KB bf16 y fragments
//   qmeta  : [2277376, 2277888)    float2[256]   (m, l) per (b, vq)
// ---------------------------------------------------------------------------

// K1: embedding gather + baseB[b][h] = b_attn[h] + W_attn[h][0:256] . h0[b]
__global__ __launch_bounds__(256) void k1_embed_base(
    const int* __restrict__ ids, const float* __restrict__ hidden,
    const float* __restrict__ emb, const float* __restrict__ W_attn,
    const float* __restrict__ b_attn,
    float* __restrict__ baseB, float* __restrict__ emb_g)
{
    const int b = blockIdx.x, h = threadIdx.x;
    __shared__ float h0[Hn];
    h0[h] = hidden[b * Hn + h];
    __syncthreads();
    float acc = b_attn[h];
    const float* wrow = W_attn + (size_t)h * K3H;
#pragma unroll 8
    for (int k = 0; k < Hn; ++k) acc += wrow[k] * h0[k];
    baseB[b * Hn + h] = acc;
    const int id = ids[b];
    emb_g[b * En + h] = emb[(size_t)id * En + h];
}

// K1b: pack W2 = W_attn[:, 256:768] into bf16 MFMA B-fragment layout.
__global__ __launch_bounds__(64) void k1b_w2frag(
    const float* __restrict__ W_attn, unsigned short* __restrict__ w2frag)
{
    const int blk = blockIdx.x;          // nt*16 + kb
    const int nt = blk >> 4, kb = blk & 15;
    const int l = threadIdx.x, lr = l & 15, lg = l >> 4;
    const int h = nt * 16 + lr;
    const float* src = W_attn + (size_t)h * K3H + Hn + kb * 32 + lg * 8;
    float4 x0 = *reinterpret_cast<const float4*>(src);
    float4 x1 = *reinterpret_cast<const float4*>(src + 4);
    reinterpret_cast<short8*>(w2frag)[(size_t)blk * 64 + l] = pack8(x0, x1);
}

// K2F: fused scores + local-softmax + context-partial.
// NEW vs round 11: depth-3 register staging (st0/st1/st2): LOADREG(kc+3) at
// iter kc, WRITEC(kc+1) uses regs loaded 2-3 chunk-periods earlier, so the
// ds_write's vmcnt wait no longer eats a full loaded-HBM latency each chunk.
// bfr issued before LOADREG (FIFO: bfr wait must not drain the A-prefetch).
__global__ __launch_bounds__(256, 2) void k2f_attn(
    const float* __restrict__ enc, const unsigned short* __restrict__ w2frag,
    const float* __restrict__ vvec, const float* __restrict__ baseB,
    float* __restrict__ part, float2* __restrict__ meta)
{
    const int tid = threadIdx.x;
    const int bx  = blockIdx.x;
    const int b   = bx & 63;
    const int cid = bx >> 6;            // t-chunk id
    const int l = tid & 63;
    const int w = tid >> 6;             // 0..3 = N-slice of 64 h
    const int lr = l & 15, lg = l >> 4;

    __shared__ unsigned short abf[64][520];   // persistent bf16 A tile
    __shared__ float red[64][5];
    __shared__ float wts[64];

    f32x4 acc[4][4];
    const f32x4 zero = {0.f, 0.f, 0.f, 0.f};
#pragma unroll
    for (int mi = 0; mi < 4; ++mi)
#pragma unroll
        for (int ni = 0; ni < 4; ++ni) acc[mi][ni] = zero;

    const short8* wf = reinterpret_cast<const short8*>(w2frag);

    const float* gbase = enc + ((size_t)(cid * 64 + w * 16 + lg) * Bn + b) * D2H
                       + lr * 4;

#define LOADREG(dst, c) do {                                                  \
    _Pragma("unroll")                                                         \
    for (int u = 0; u < 4; ++u)                                               \
        dst[u] = *reinterpret_cast<const float4*>(                            \
            gbase + (size_t)u * 131072 + (c) * 64);                           \
    } while (0)

#define WRITEC(src, c) do {                                                   \
    _Pragma("unroll")                                                         \
    for (int u = 0; u < 4; ++u)                                               \
        *reinterpret_cast<uint2*>(&abf[w * 16 + u * 4 + lg][(c) * 64 + lr * 4])\
            = pack4(src[u]);                                                  \
    } while (0)

#define COMPUTE_KB(kb, bfr) do {                                              \
    _Pragma("unroll")                                                         \
    for (int mi = 0; mi < 4; ++mi) {                                          \
        short8 a = *reinterpret_cast<const short8*>(                          \
            &abf[mi * 16 + lr][(kb) * 32 + lg * 8]);                          \
        _Pragma("unroll")                                                     \
        for (int ni = 0; ni < 4; ++ni)                                        \
            acc[mi][ni] = __builtin_amdgcn_mfma_f32_16x16x32_bf16(            \
                a, bfr[ni], acc[mi][ni], 0, 0, 0);                            \
    } } while (0)

    float4 st0[4], st1[4], st2[4];
    // prologue: chunks 0,1,2 issued (depth-3 fill); chunk 0 written
    LOADREG(st0, 0);
    LOADREG(st1, 1);
    LOADREG(st2, 2);
    WRITEC(st0, 0);                      // waits st0 only (oldest, FIFO)
    asm volatile("s_waitcnt lgkmcnt(0)" ::: "memory");
    __builtin_amdgcn_s_barrier();
    __builtin_amdgcn_sched_barrier(0);

#pragma unroll
    for (int kc = 0; kc < 8; ++kc) {
        short8 bfr0[4], bfr1[4];
#pragma unroll
        for (int ni = 0; ni < 4; ++ni)
            bfr0[ni] = wf[(size_t)(((w * 4 + ni) * 16) + 2 * kc) * 64 + l];
#pragma unroll
        for (int ni = 0; ni < 4; ++ni)
            bfr1[ni] = wf[(size_t)(((w * 4 + ni) * 16) + 2 * kc + 1) * 64 + l];
        __builtin_amdgcn_sched_barrier(0);   // pin: bfr issued before LOADREG
        if (kc < 5) {
            if ((kc % 3) == 0)      LOADREG(st0, kc + 3);
            else if ((kc % 3) == 1) LOADREG(st1, kc + 3);
            else                    LOADREG(st2, kc + 3);
        }
        COMPUTE_KB(2 * kc,     bfr0);
        COMPUTE_KB(2 * kc + 1, bfr1);
        if (kc < 7) {
            const int wb = (kc + 1) % 3;
            if (wb == 0)      WRITEC(st0, kc + 1);
            else if (wb == 1) WRITEC(st1, kc + 1);
            else              WRITEC(st2, kc + 1);
        }
        asm volatile("s_waitcnt lgkmcnt(0)" ::: "memory");
        __builtin_amdgcn_s_barrier();
        __builtin_amdgcn_sched_barrier(0);
    }
#undef LOADREG
#undef WRITEC
#undef COMPUTE_KB

    // scores epilogue
    float psum[4][4];
#pragma unroll
    for (int mi = 0; mi < 4; ++mi)
#pragma unroll
        for (int r = 0; r < 4; ++r) psum[mi][r] = 0.f;
#pragma unroll
    for (int ni = 0; ni < 4; ++ni) {
        const int h = w * 64 + ni * 16 + lr;
        const float vh = vvec[h];
        const float bt = baseB[b * Hn + h];
#pragma unroll
        for (int mi = 0; mi < 4; ++mi)
#pragma unroll
            for (int r = 0; r < 4; ++r)
                psum[mi][r] += vh * tanhf(acc[mi][ni][r] + bt);
    }
#pragma unroll
    for (int d = 1; d < 16; d <<= 1)
#pragma unroll
        for (int mi = 0; mi < 4; ++mi)
#pragma unroll
            for (int r = 0; r < 4; ++r)
                psum[mi][r] += __shfl_xor(psum[mi][r], d, 64);
    if (lr == 0) {
#pragma unroll
        for (int mi = 0; mi < 4; ++mi)
#pragma unroll
            for (int r = 0; r < 4; ++r)
                red[mi * 16 + lg * 4 + r][w] = psum[mi][r];
    }
    __syncthreads();

    if (tid < 64) {
        float s = red[tid][0] + red[tid][1] + red[tid][2] + red[tid][3];
        float m = s;
#pragma unroll
        for (int d = 1; d < 64; d <<= 1) m = fmaxf(m, __shfl_xor(m, d, 64));
        const float e = expf(s - m);
        float lsum = e;
#pragma unroll
        for (int d = 1; d < 64; d <<= 1) lsum += __shfl_xor(lsum, d, 64);
        wts[tid] = e;
        if (tid == 0) meta[bx] = make_float2(m, lsum);
    }
    __syncthreads();

    const int d0 = tid * 2;
    float c0 = 0.f, c1 = 0.f;
#pragma unroll 4
    for (int t = 0; t < 64; ++t) {
        const float wt = wts[t];
        const unsigned u = *reinterpret_cast<const unsigned*>(&abf[t][d0]);
        c0 += wt * bf2f((unsigned short)(u & 0xffffu));
        c1 += wt * bf2f((unsigned short)(u >> 16));
    }
    float* pp = part + (size_t)bx * 512 + d0;
    pp[0] = c0; pp[1] = c1;
}

// K56: cross-chunk softmax combine -> ctx (LDS + y) then GRU. Merged k5n+k6.
__global__ __launch_bounds__(256) void k56_ctx_gru(
    const float* __restrict__ part, const float2* __restrict__ meta,
    const float* __restrict__ hidden, const float* __restrict__ emb_g,
    const float* __restrict__ W_comb, const float* __restrict__ b_comb,
    const float* __restrict__ W_ih, const float* __restrict__ W_hh,
    const float* __restrict__ b_ih, const float* __restrict__ b_hh,
    float* __restrict__ y, float* __restrict__ out_hidden)
{
    const int b = blockIdx.x, tid = threadIdx.x;
    __shared__ float sc[64];
    __shared__ float in_[K3H];
    __shared__ float h0[Hn];
    __shared__ float comb[Hn];
    __shared__ float gx[K3H], gh[K3H];
    if (tid < 64) {
        const float2 ml = meta[(size_t)tid * 64 + b];
        float M = ml.x;
#pragma unroll
        for (int d = 1; d < 64; d <<= 1) M = fmaxf(M, __shfl_xor(M, d, 64));
        const float e = expf(ml.x - M);
        float L = e * ml.y;
#pragma unroll
        for (int d = 1; d < 64; d <<= 1) L += __shfl_xor(L, d, 64);
        sc[tid] = e / L;
    }
    in_[512 + tid] = emb_g[b * En + tid];
    h0[tid] = hidden[b * Hn + tid];
    __syncthreads();
    {
        const int d0 = tid * 2;
        float c0 = 0.f, c1 = 0.f;
#pragma unroll 4
        for (int c = 0; c < 64; ++c) {
            const float s = sc[c];
            const float2 p = *reinterpret_cast<const float2*>(
                part + ((size_t)c * 64 + b) * 512 + d0);
            c0 += s * p.x; c1 += s * p.y;
        }
        in_[d0] = c0; in_[d0 + 1] = c1;
        y[(size_t)b * K3H + Hn + d0]     = c0;
        y[(size_t)b * K3H + Hn + d0 + 1] = c1;
    }
    __syncthreads();
    {
        float c = b_comb[tid];
        const float* wr = W_comb + (size_t)tid * K3H;
#pragma unroll 8
        for (int k = 0; k < K3H; ++k) c += wr[k] * in_[k];
        comb[tid] = c;
    }
    __syncthreads();
#pragma unroll
    for (int p = 0; p < 3; ++p) {
        const int g = p * 256 + tid;
        float a = b_ih[g], bh = b_hh[g];
        const float* wi = W_ih + (size_t)g * Hn;
        const float* wh = W_hh + (size_t)g * Hn;
#pragma unroll 8
        for (int k = 0; k < Hn; ++k) { a += wi[k] * comb[k]; bh += wh[k] * h0[k]; }
        gx[g] = a; gh[g] = bh;
    }
    __syncthreads();
    const float r = 1.f / (1.f + expf(-(gx[tid] + gh[tid])));
    const float z = 1.f / (1.f + expf(-(gx[256 + tid] + gh[256 + tid])));
    const float n = tanhf(gx[512 + tid] + r * gh[512 + tid]);
    const float hn = (1.f - z) * n + z * h0[tid];
    y[(size_t)b * K3H + tid] = hn;
    out_hidden[b * Hn + tid] = hn;
}

// K7Y: pack y (64b x 768k) into bf16 MFMA B-fragment layout.
__global__ __launch_bounds__(64) void k7y_pack(
    const float* __restrict__ y, unsigned short* __restrict__ yfrag)
{
    const int blk = blockIdx.x;          // 0..95 = ni*24 + kb
    const int ni = blk / 24, kb = blk % 24;
    const int l = threadIdx.x, lr = l & 15, lg = l >> 4;
    const int b = ni * 16 + lr;
    const float* src = y + (size_t)b * K3H + kb * 32 + lg * 8;
    float4 x0 = *reinterpret_cast<const float4*>(src);
    float4 x1 = *reinterpret_cast<const float4*>(src + 4);
    reinterpret_cast<short8*>(yfrag)[(size_t)blk * 64 + l] = pack8(x0, x1);
}

// K7: logits GEMM via MFMA; W_out streamed global->reg->bf16; yfrag from L2.
__global__ __launch_bounds__(256) void k7_logits(
    const float* __restrict__ W_out, const float* __restrict__ b_out,
    const unsigned short* __restrict__ yfrag, float* __restrict__ out)
{
    const int tid = threadIdx.x;
    const int vbase = blockIdx.x * 64;
    const int l = tid & 63, w = tid >> 6;
    const int lr = l & 15, lg = l >> 4;

    const short8* yf = reinterpret_cast<const short8*>(yfrag);

    f32x4 acc[4];
    const f32x4 zero = {0.f, 0.f, 0.f, 0.f};
#pragma unroll
    for (int ni = 0; ni < 4; ++ni) acc[ni] = zero;

    int v = vbase + w * 16 + lr;
    if (v >= Vn) v = Vn - 1;
    const float* wrow = W_out + (size_t)v * K3H + lg * 8;

#pragma unroll 4
    for (int kb = 0; kb < 24; ++kb) {
        float4 x0 = *reinterpret_cast<const float4*>(wrow + kb * 32);
        float4 x1 = *reinterpret_cast<const float4*>(wrow + kb * 32 + 4);
        short8 a = pack8(x0, x1);
#pragma unroll
        for (int ni = 0; ni < 4; ++ni) {
            short8 bf = yf[(size_t)(ni * 24 + kb) * 64 + l];
            acc[ni] = __builtin_amdgcn_mfma_f32_16x16x32_bf16(
                a, bf, acc[ni], 0, 0, 0);
        }
    }

    __shared__ float lt[64][65];
#pragma unroll
    for (int ni = 0; ni < 4; ++ni)
#pragma unroll
        for (int r = 0; r < 4; ++r)
            lt[w * 16 + lg * 4 + r][ni * 16 + lr] = acc[ni][r];
    __syncthreads();

#pragma unroll
    for (int u = 0; u < 16; ++u) {
        const int idx = tid + u * 256;
        const int bb = idx >> 6, vv = idx & 63;
        const int vo = vbase + vv;
        if (vo < Vn)
            out[(size_t)bb * Vn + vo] = lt[vv][bb] + b_out[vo];
    }
}

#define VQ 12565   // ceil(Vn/4)

// K8A: per-(b, quarter) partial max + sum(exp)
__global__ __launch_bounds__(1024) void k8a_partial(
    const float* __restrict__ out, float2* __restrict__ qmeta)
{
    const int b = blockIdx.x, q = blockIdx.y;
    const int lo = q * VQ, hi = (lo + VQ < Vn) ? lo + VQ : Vn;
    const float* row = out + (size_t)b * Vn;
    __shared__ float red[1024];
    float m = -1e30f;
    for (int i = lo + threadIdx.x; i < hi; i += 1024) m = fmaxf(m, row[i]);
    red[threadIdx.x] = m; __syncthreads();
    for (int s = 512; s > 0; s >>= 1) {
        if (threadIdx.x < s) red[threadIdx.x] = fmaxf(red[threadIdx.x], red[threadIdx.x + s]);
        __syncthreads();
    }
    m = red[0]; __syncthreads();
    float l = 0.f;
    for (int i = lo + threadIdx.x; i < hi; i += 1024) l += expf(row[i] - m);
    red[threadIdx.x] = l; __syncthreads();
    for (int s = 512; s > 0; s >>= 1) {
        if (threadIdx.x < s) red[threadIdx.x] += red[threadIdx.x + s];
        __syncthreads();
    }
    if (threadIdx.x == 0) qmeta[b * 4 + q] = make_float2(m, red[0]);
}

// K8B: combine quarters -> offset; subtract over the quarter's range
__global__ __launch_bounds__(1024) void k8b_apply(
    float* __restrict__ out, const float2* __restrict__ qmeta)
{
    const int b = blockIdx.x, q = blockIdx.y;
    const int lo = q * VQ, hi = (lo + VQ < Vn) ? lo + VQ : Vn;
    float2 q0 = qmeta[b * 4 + 0], q1 = qmeta[b * 4 + 1];
    float2 q2 = qmeta[b * 4 + 2], q3 = qmeta[b * 4 + 3];
    const float M = fmaxf(fmaxf(q0.x, q1.x), fmaxf(q2.x, q3.x));
    const float L = q0.y * expf(q0.x - M) + q1.y * expf(q1.x - M)
                  + q2.y * expf(q2.x - M) + q3.y * expf(q3.x - M);
    const float off = M + logf(L);
    float* row = out + (size_t)b * Vn;
    for (int i = lo + threadIdx.x; i < hi; i += 1024) row[i] -= off;
}

extern "C" void kernel_launch(void* const* d_in, const int* in_sizes, int n_in,
                              void* d_out, int out_size, void* d_ws, size_t ws_size,
                              hipStream_t stream)
{
    const int*   ids    = (const int*)d_in[0];
    const float* hidden = (const float*)d_in[1];
    const float* enc    = (const float*)d_in[2];
    const float* emb    = (const float*)d_in[3];
    const float* W_attn = (const float*)d_in[4];
    const float* b_attn = (const float*)d_in[5];
    const float* vvec   = (const float*)d_in[6];
    const float* W_comb = (const float*)d_in[7];
    const float* b_comb = (const float*)d_in[8];
    const float* W_ih   = (const float*)d_in[9];
    const float* W_hh   = (const float*)d_in[10];
    const float* b_ih   = (const float*)d_in[11];
    const float* b_hh   = (const float*)d_in[12];
    const float* W_out  = (const float*)d_in[13];
    const float* b_out  = (const float*)d_in[14];

    float* out = (float*)d_out;
    float* ws = (float*)d_ws;
    float*  baseB = ws;                               // 16384
    float*  emb_g = ws + 16384;                       // 16384
    float2* meta  = (float2*)(ws + 32768);            // 4096 float2
    float*  part  = ws + 40960;                       // 2097152
    float*  y     = ws + 2138112;                     // 49152
    unsigned short* w2frag = (unsigned short*)(ws + 2187264); // 131072 bf16
    unsigned short* yfrag  = (unsigned short*)(ws + 2252800); // 49152 bf16
    float2* qmeta = (float2*)(ws + 2277376);          // 256 float2

    hipLaunchKernelGGL(k1_embed_base, dim3(Bn), dim3(256), 0, stream,
                       ids, hidden, emb, W_attn, b_attn, baseB, emb_g);
    hipLaunchKernelGGL(k1b_w2frag, dim3(256), dim3(64), 0, stream,
                       W_attn, w2frag);
    hipLaunchKernelGGL(k2f_attn, dim3(4096), dim3(256), 0, stream,
                       enc, w2frag, vvec, baseB, part, meta);
    hipLaunchKernelGGL(k56_ctx_gru, dim3(Bn), dim3(256), 0, stream,
                       part, meta, hidden, emb_g, W_comb, b_comb,
                       W_ih, W_hh, b_ih, b_hh, y, out + (size_t)Bn * Vn);
    hipLaunchKernelGGL(k7y_pack, dim3(96), dim3(64), 0, stream, y, yfrag);
    hipLaunchKernelGGL(k7_logits, dim3((Vn + 63) / 64), dim3(256), 0, stream,
                       W_out, b_out, yfrag, out);
    hipLaunchKernelGGL(k8a_partial, dim3(Bn, 4), dim3(1024), 0, stream,
                       out, qmeta);
    hipLaunchKernelGGL(k8b_apply, dim3(Bn, 4), dim3(1024), 0, stream,
                       out, qmeta);
}